// Round 1
// baseline (7833.018 us; speedup 1.0000x reference)
//
#include <hip/hip_runtime.h>
#include <math.h>

// Problem constants
#define B_  64
#define W_  128
#define L_  32
#define V_  128
#define E_  128
#define H_  256
#define G4_ 1024      // 4*H
#define NW  8192      // B*W words

// ---------------------------------------------------------------------------
// K1: emb_proj[dir][v][g] = dot(emb_table[v], Wih_dir[g]) + bih_dir[g] + bhh_dir[g]
// grid: 256 blocks (dir*128 + v), block: 256 threads, each thread 4 g values.
// ---------------------------------------------------------------------------
__global__ __launch_bounds__(256) void k_embproj(
    const float* __restrict__ emb,
    const float* __restrict__ Wih_f, const float* __restrict__ bih_f, const float* __restrict__ bhh_f,
    const float* __restrict__ Wih_b, const float* __restrict__ bih_b, const float* __restrict__ bhh_b,
    float* __restrict__ eproj) {
  int v   = blockIdx.x & (V_ - 1);
  int dir = blockIdx.x >> 7;
  const float* Wih = dir ? Wih_b : Wih_f;
  const float* b1  = dir ? bih_b : bih_f;
  const float* b2  = dir ? bhh_b : bhh_f;
  __shared__ float es[E_];
  if (threadIdx.x < E_) es[threadIdx.x] = emb[v * E_ + threadIdx.x];
  __syncthreads();
#pragma unroll
  for (int q = 0; q < 4; ++q) {
    int g = q * 256 + threadIdx.x;
    const float* wr = Wih + g * E_;
    float a = 0.f;
#pragma unroll 4
    for (int k = 0; k < E_; k += 4) {
      float4 w4 = *(const float4*)(wr + k);
      float4 e4 = *(const float4*)(es + k);
      a += w4.x * e4.x + w4.y * e4.y + w4.z * e4.z + w4.w * e4.w;
    }
    eproj[(dir * V_ + v) * G4_ + g] = a + b1[g] + b2[g];
  }
}

// ---------------------------------------------------------------------------
// K2: BiLSTM recurrence. One block = M_ words, one direction (blockIdx.y).
// Thread j owns gate rows {j, 256+j, 512+j, 768+j} of Whh and element j of h/c.
// k-chunk outer / word inner so Whh registers amortize over M_ words.
// h lives in LDS (same-address broadcast reads across lanes: conflict-free).
// ---------------------------------------------------------------------------
#define M_ 8
__global__ __launch_bounds__(256) void k_lstm(
    const int* __restrict__ char_ids, const int* __restrict__ word_lens,
    const float* __restrict__ eproj,
    const float* __restrict__ Whh_f, const float* __restrict__ Whh_b,
    float* __restrict__ hcat) {
  const int tid = threadIdx.x;
  const int w0  = blockIdx.x * M_;
  const int dir = blockIdx.y;   // 0 = forward, 1 = backward

  __shared__ float h_s[M_][H_];     // 8 KB
  __shared__ int   ids_s[M_][L_];   // 1 KB
  __shared__ int   len_s[M_];

  for (int i = tid; i < M_ * L_; i += 256) ((int*)ids_s)[i] = char_ids[w0 * L_ + i];
  if (tid < M_) len_s[tid] = word_lens[w0 + tid];
#pragma unroll
  for (int m = 0; m < M_; ++m) h_s[m][tid] = 0.f;
  float c_r[M_];
#pragma unroll
  for (int m = 0; m < M_; ++m) c_r[m] = 0.f;
  __syncthreads();

  const float* Whh = dir ? Whh_b : Whh_f;
  const float* ep  = eproj + dir * (V_ * G4_);
  const float* wr0 = Whh + (0 * H_ + tid) * H_;
  const float* wr1 = Whh + (1 * H_ + tid) * H_;
  const float* wr2 = Whh + (2 * H_ + tid) * H_;
  const float* wr3 = Whh + (3 * H_ + tid) * H_;

  int mlen = 0;
#pragma unroll
  for (int m = 0; m < M_; ++m) mlen = max(mlen, len_s[m]);

  for (int t = 0; t < mlen; ++t) {
    float acc0[M_], acc1[M_], acc2[M_], acc3[M_];
#pragma unroll
    for (int m = 0; m < M_; ++m) { acc0[m] = 0.f; acc1[m] = 0.f; acc2[m] = 0.f; acc3[m] = 0.f; }

#pragma unroll 2
    for (int k = 0; k < H_; k += 4) {
      float4 w0v = *(const float4*)(wr0 + k);
      float4 w1v = *(const float4*)(wr1 + k);
      float4 w2v = *(const float4*)(wr2 + k);
      float4 w3v = *(const float4*)(wr3 + k);
#pragma unroll
      for (int m = 0; m < M_; ++m) {
        float4 hv = *(const float4*)(&h_s[m][k]);
        acc0[m] += hv.x * w0v.x + hv.y * w0v.y + hv.z * w0v.z + hv.w * w0v.w;
        acc1[m] += hv.x * w1v.x + hv.y * w1v.y + hv.z * w1v.z + hv.w * w1v.w;
        acc2[m] += hv.x * w2v.x + hv.y * w2v.y + hv.z * w2v.z + hv.w * w2v.w;
        acc3[m] += hv.x * w3v.x + hv.y * w3v.y + hv.z * w3v.z + hv.w * w3v.w;
      }
    }

    __syncthreads();  // all reads of h_s done before anyone writes

#pragma unroll
    for (int m = 0; m < M_; ++m) {
      const int len = len_s[m];
      if (t < len) {
        const int tt = dir ? (len - 1 - t) : t;   // backward walks len-1 .. 0
        const int id = ids_s[m][tt];
        const float* xw = ep + id * G4_;
        float gi = acc0[m] + xw[tid];
        float gf = acc1[m] + xw[H_ + tid];
        float gg = acc2[m] + xw[2 * H_ + tid];
        float go = acc3[m] + xw[3 * H_ + tid];
        float si = 1.f / (1.f + __expf(-gi));
        float sf = 1.f / (1.f + __expf(-gf));
        float so = 1.f / (1.f + __expf(-go));
        float tg = 2.f / (1.f + __expf(-2.f * gg)) - 1.f;    // tanh(gg)
        float cn = sf * c_r[m] + si * tg;
        c_r[m] = cn;
        float tc = 2.f / (1.f + __expf(-2.f * cn)) - 1.f;    // tanh(cn)
        h_s[m][tid] = so * tc;
      }
    }
    __syncthreads();
  }

  // concat layout: [0:256] = h_bwd, [256:512] = h_fwd
#pragma unroll
  for (int m = 0; m < M_; ++m)
    hcat[(w0 + m) * (2 * H_) + (dir ? 0 : H_) + tid] = h_s[m][tid];
}

// ---------------------------------------------------------------------------
// K3: wemb[n][j] = pb[j] + sum_k pW[j][k] * hcat[n][k];  also writes lens_out.
// Block = 16 words staged in LDS, thread j computes output column j.
// ---------------------------------------------------------------------------
#define PM_ 16
__global__ __launch_bounds__(256) void k_proj(
    const float* __restrict__ hcat, const float* __restrict__ pW,
    const float* __restrict__ pb, float* __restrict__ out) {
  const int tid = threadIdx.x;
  const int n0  = blockIdx.x * PM_;
  __shared__ float hs[PM_][2 * H_];   // 32 KB
  for (int i = tid; i < PM_ * 2 * H_; i += 256) ((float*)hs)[i] = hcat[n0 * 2 * H_ + i];
  __syncthreads();

  const float* pwr = pW + tid * (2 * H_);
  float acc[PM_];
#pragma unroll
  for (int m = 0; m < PM_; ++m) acc[m] = 0.f;

#pragma unroll 2
  for (int k = 0; k < 2 * H_; k += 4) {
    float4 w4 = *(const float4*)(pwr + k);
#pragma unroll
    for (int m = 0; m < PM_; ++m) {
      float4 h4 = *(const float4*)(&hs[m][k]);
      acc[m] += w4.x * h4.x + w4.y * h4.y + w4.z * h4.z + w4.w * h4.w;
    }
  }
  const float bias = pb[tid];
#pragma unroll
  for (int m = 0; m < PM_; ++m) out[(n0 + m) * H_ + tid] = acc[m] + bias;

  // Output 1: lens_out = full((B,), W)  — flat f32 slots after the (B,W,H) out.
  if (blockIdx.x == 0 && tid < B_) out[NW * H_ + tid] = (float)W_;
}

// ---------------------------------------------------------------------------
extern "C" void kernel_launch(void* const* d_in, const int* in_sizes, int n_in,
                              void* d_out, int out_size, void* d_ws, size_t ws_size,
                              hipStream_t stream) {
  const int*   char_ids  = (const int*)  d_in[0];
  const int*   word_lens = (const int*)  d_in[1];
  const float* emb       = (const float*)d_in[2];
  const float* Wih_f     = (const float*)d_in[3];
  const float* Whh_f     = (const float*)d_in[4];
  const float* bih_f     = (const float*)d_in[5];
  const float* bhh_f     = (const float*)d_in[6];
  const float* Wih_b     = (const float*)d_in[7];
  const float* Whh_b     = (const float*)d_in[8];
  const float* bih_b     = (const float*)d_in[9];
  const float* bhh_b     = (const float*)d_in[10];
  const float* pW        = (const float*)d_in[11];
  const float* pb        = (const float*)d_in[12];
  float* out = (float*)d_out;

  // workspace: eproj (2*V*4H floats = 1 MB) | hcat (NW*2H floats = 16 MB)
  float* eproj = (float*)d_ws;
  float* hcat  = eproj + 2 * V_ * G4_;

  k_embproj<<<dim3(2 * V_), dim3(256), 0, stream>>>(emb, Wih_f, bih_f, bhh_f,
                                                    Wih_b, bih_b, bhh_b, eproj);
  k_lstm<<<dim3(NW / M_, 2), dim3(256), 0, stream>>>(char_ids, word_lens, eproj,
                                                     Whh_f, Whh_b, hcat);
  k_proj<<<dim3(NW / PM_), dim3(256), 0, stream>>>(hcat, pW, pb, out);
}

// Round 2
// 5556.722 us; speedup vs baseline: 1.4096x; 1.4096x over previous
//
#include <hip/hip_runtime.h>
#include <hip/hip_bf16.h>
#include <math.h>

// Problem constants
#define B_  64
#define W_  128
#define L_  32
#define V_  128
#define E_  128
#define H_  256
#define G4_ 1024      // 4*H
#define NW  8192      // B*W words
#define KS_ 12        // MFMA k-steps: 8 for h (K=256) + 4 for one-hot chars (V=128)
#define KPAD 400      // padded LDS row (bf16 elems): 384 used + 16 pad
#define M_  16        // words per block

typedef short s8v  __attribute__((ext_vector_type(8)));  // 8 bf16 (4 VGPR)
typedef float f4v  __attribute__((ext_vector_type(4)));

// ---------------------------------------------------------------------------
// K1: eproj[dir][v][g] = dot(emb[v], Wih_dir[g]) + bih[g] + bhh[g]   (fp32)
// ---------------------------------------------------------------------------
__global__ __launch_bounds__(256) void k_embproj(
    const float* __restrict__ emb,
    const float* __restrict__ Wih_f, const float* __restrict__ bih_f, const float* __restrict__ bhh_f,
    const float* __restrict__ Wih_b, const float* __restrict__ bih_b, const float* __restrict__ bhh_b,
    float* __restrict__ eproj) {
  int v   = blockIdx.x & (V_ - 1);
  int dir = blockIdx.x >> 7;
  const float* Wih = dir ? Wih_b : Wih_f;
  const float* b1  = dir ? bih_b : bih_f;
  const float* b2  = dir ? bhh_b : bhh_f;
  __shared__ float es[E_];
  if (threadIdx.x < E_) es[threadIdx.x] = emb[v * E_ + threadIdx.x];
  __syncthreads();
#pragma unroll
  for (int q = 0; q < 4; ++q) {
    int g = q * 256 + threadIdx.x;
    const float* wr = Wih + g * E_;
    float a = 0.f;
#pragma unroll 4
    for (int k = 0; k < E_; k += 4) {
      float4 w4 = *(const float4*)(wr + k);
      float4 e4 = *(const float4*)(es + k);
      a += w4.x * e4.x + w4.y * e4.y + w4.z * e4.z + w4.w * e4.w;
    }
    eproj[(dir * V_ + v) * G4_ + g] = a + b1[g] + b2[g];
  }
}

// ---------------------------------------------------------------------------
// K1b: pack B = [Whh^T ; eproj] (384 x 1024) per dir into MFMA B-fragment
// layout, bf16.  Element (ks, nt, lane, j) holds Bmat[k][n] with
//   k = ks*32 + (lane>>4)*8 + j,  n = nt*16 + (lane&15)
//   k <  256 : Whh[n][k]
//   k >= 256 : eproj[k-256][n]   (one-hot char rows, biases folded in)
// One global_load_dwordx4 per (frag, lane) at runtime, fully coalesced.
// ---------------------------------------------------------------------------
__global__ __launch_bounds__(64) void k_pack(
    const float* __restrict__ eproj,
    const float* __restrict__ Whh_f, const float* __restrict__ Whh_b,
    __hip_bfloat16* __restrict__ Bpack) {
  const int lane = threadIdx.x;
  const int nt   = blockIdx.x & 63;
  const int ks   = (blockIdx.x >> 6) % KS_;
  const int dir  = blockIdx.x / (64 * KS_);
  const float* Whh = dir ? Whh_b : Whh_f;
  const int n  = nt * 16 + (lane & 15);
  const int k0 = ks * 32 + (lane >> 4) * 8;
  size_t base = (((size_t)(dir * KS_ + ks) * 64 + nt) * 64 + lane) * 8;
#pragma unroll
  for (int j = 0; j < 8; ++j) {
    int k = k0 + j;
    float v = (k < H_) ? Whh[n * H_ + k]
                       : eproj[(dir * V_ + (k - H_)) * G4_ + n];
    Bpack[base + j] = __float2bfloat16(v);
  }
}

// ---------------------------------------------------------------------------
// K2: MFMA BiLSTM recurrence. Block = 16 words x 1 dir, 4 waves.
// Wave w owns gate positions [w*64, w*64+64) across all 4 gate groups
// -> 16 acc tiles.  A = [h | onehot(char)] as bf16 in LDS.
// C/D layout (verified m89): word m = (lane>>4)*4 + reg, col = lane&15.
// ---------------------------------------------------------------------------
__global__ __launch_bounds__(256, 2) void k_lstm(
    const int* __restrict__ char_ids, const int* __restrict__ word_lens,
    const __hip_bfloat16* __restrict__ Bpack, float* __restrict__ hcat) {
  const int tid  = threadIdx.x;
  const int lane = tid & 63;
  const int w    = tid >> 6;       // wave 0..3
  const int w0   = blockIdx.x * M_;
  const int dir  = blockIdx.y;     // 0 fwd, 1 bwd

  __shared__ unsigned short hL[M_][KPAD];  // 12.8 KB: [h bf16 256 | onehot 128 | pad]
  __shared__ int ids_s[M_][L_];
  __shared__ int len_s[M_];

  for (int i = tid; i < M_ * L_; i += 256) ((int*)ids_s)[i] = char_ids[w0 * L_ + i];
  if (tid < M_) len_s[tid] = word_lens[w0 + tid];
  for (int i = tid; i < M_ * KPAD / 2; i += 256) ((unsigned int*)hL)[i] = 0u;
  __syncthreads();

  // one-hot for t=0
  if (tid < M_) {
    int len = len_s[tid];
    int tt  = dir ? (len - 1) : 0;
    hL[tid][H_ + ids_s[tid][tt]] = 0x3F80;  // bf16 1.0
  }
  int mlen = 0;
#pragma unroll
  for (int m = 0; m < M_; ++m) mlen = max(mlen, len_s[m]);
  int lr[4];
#pragma unroll
  for (int r = 0; r < 4; ++r) lr[r] = len_s[((lane >> 4) << 2) + r];
  __syncthreads();

  const char* Bb = (const char*)(Bpack + (size_t)dir * (KS_ * 64 * 64 * 8));
  const char* arow = (const char*)&hL[lane & 15][0];
  const int   aoff = (lane >> 4) << 4;   // byte offset of this lane's 8 k-elems

  float c_[4][4];                        // [jj][r]
#pragma unroll
  for (int jj = 0; jj < 4; ++jj)
#pragma unroll
    for (int r = 0; r < 4; ++r) c_[jj][r] = 0.f;

  for (int t = 0; t < mlen; ++t) {
    // A fragments for all 12 k-steps (h state + one-hot, step t)
    s8v af[KS_];
#pragma unroll
    for (int ks = 0; ks < KS_; ++ks)
      af[ks] = *(const s8v*)(arow + ks * 64 + aoff);

    f4v acc[4][4];                       // [gate group u][subtile jj]
#pragma unroll
    for (int u = 0; u < 4; ++u)
#pragma unroll
      for (int jj = 0; jj < 4; ++jj) acc[u][jj] = (f4v){0.f, 0.f, 0.f, 0.f};

#pragma unroll
    for (int ks = 0; ks < KS_; ++ks) {
#pragma unroll
      for (int u = 0; u < 4; ++u) {
#pragma unroll
        for (int jj = 0; jj < 4; ++jj) {
          const int nt = u * 16 + w * 4 + jj;
          s8v bf = *(const s8v*)(Bb + (((size_t)ks * 64 + nt) * 64 + lane) * 16);
          acc[u][jj] = __builtin_amdgcn_mfma_f32_16x16x32_bf16(af[ks], bf, acc[u][jj], 0, 0, 0);
        }
      }
    }

    __syncthreads();   // all waves done reading hL for step t

    // elementwise gates + masked state update; write h_new (bf16) to LDS
#pragma unroll
    for (int jj = 0; jj < 4; ++jj) {
#pragma unroll
      for (int r = 0; r < 4; ++r) {
        const int m = ((lane >> 4) << 2) + r;
        const int p = (w * 4 + jj) * 16 + (lane & 15);
        float gi = acc[0][jj][r];
        float gf = acc[1][jj][r];
        float gg = acc[2][jj][r];
        float go = acc[3][jj][r];
        float si = 1.f / (1.f + __expf(-gi));
        float sf = 1.f / (1.f + __expf(-gf));
        float so = 1.f / (1.f + __expf(-go));
        float tg = 2.f / (1.f + __expf(-2.f * gg)) - 1.f;
        float cn = sf * c_[jj][r] + si * tg;
        float hn = so * (2.f / (1.f + __expf(-2.f * cn)) - 1.f);
        if (t < lr[r]) {
          c_[jj][r] = cn;
          union { __hip_bfloat16 b; unsigned short u; } cv;
          cv.b = __float2bfloat16(hn);
          hL[m][p] = cv.u;
        }
      }
    }
    // advance one-hot to step t+1
    if (tid < M_ && t + 1 < mlen) {
      int len  = len_s[tid];
      int told = dir ? max(len - 1 - t, 0)       : min(t, len - 1);
      int tnew = dir ? max(len - 1 - (t + 1), 0) : min(t + 1, len - 1);
      hL[tid][H_ + ids_s[tid][told]] = 0;
      hL[tid][H_ + ids_s[tid][tnew]] = 0x3F80;
    }
    __syncthreads();   // h(t+1) + one-hot(t+1) visible
  }

  // write frozen h to hcat: concat = [h_bwd | h_fwd]
  const int off = dir ? 0 : H_;
#pragma unroll
  for (int q = 0; q < M_; ++q) {
    unsigned int ui = ((unsigned int)hL[q][tid]) << 16;
    hcat[(size_t)(w0 + q) * (2 * H_) + off + tid] = __uint_as_float(ui);
  }
}

// ---------------------------------------------------------------------------
// K3: wemb = hcat @ pW^T + pb;  also writes lens_out (= W) slots.
// ---------------------------------------------------------------------------
#define PM_ 16
__global__ __launch_bounds__(256) void k_proj(
    const float* __restrict__ hcat, const float* __restrict__ pW,
    const float* __restrict__ pb, float* __restrict__ out) {
  const int tid = threadIdx.x;
  const int n0  = blockIdx.x * PM_;
  __shared__ float hs[PM_][2 * H_];   // 32 KB
  for (int i = tid; i < PM_ * 2 * H_; i += 256) ((float*)hs)[i] = hcat[n0 * 2 * H_ + i];
  __syncthreads();

  const float* pwr = pW + tid * (2 * H_);
  float acc[PM_];
#pragma unroll
  for (int m = 0; m < PM_; ++m) acc[m] = 0.f;

#pragma unroll 2
  for (int k = 0; k < 2 * H_; k += 4) {
    float4 w4 = *(const float4*)(pwr + k);
#pragma unroll
    for (int m = 0; m < PM_; ++m) {
      float4 h4 = *(const float4*)(&hs[m][k]);
      acc[m] += w4.x * h4.x + w4.y * h4.y + w4.z * h4.z + w4.w * h4.w;
    }
  }
  const float bias = pb[tid];
#pragma unroll
  for (int m = 0; m < PM_; ++m) out[(n0 + m) * H_ + tid] = acc[m] + bias;

  if (blockIdx.x == 0 && tid < B_) out[NW * H_ + tid] = (float)W_;
}

// ---------------------------------------------------------------------------
extern "C" void kernel_launch(void* const* d_in, const int* in_sizes, int n_in,
                              void* d_out, int out_size, void* d_ws, size_t ws_size,
                              hipStream_t stream) {
  const int*   char_ids  = (const int*)  d_in[0];
  const int*   word_lens = (const int*)  d_in[1];
  const float* emb       = (const float*)d_in[2];
  const float* Wih_f     = (const float*)d_in[3];
  const float* Whh_f     = (const float*)d_in[4];
  const float* bih_f     = (const float*)d_in[5];
  const float* bhh_f     = (const float*)d_in[6];
  const float* Wih_b     = (const float*)d_in[7];
  const float* Whh_b     = (const float*)d_in[8];
  const float* bih_b     = (const float*)d_in[9];
  const float* bhh_b     = (const float*)d_in[10];
  const float* pW        = (const float*)d_in[11];
  const float* pb        = (const float*)d_in[12];
  float* out = (float*)d_out;

  // ws: [Bpack 1.5MB][eproj 1MB / hcat 16MB union]  (eproj dead after k_pack)
  const size_t BPACK_ELEMS = (size_t)2 * KS_ * 64 * 64 * 8;
  __hip_bfloat16* Bpack = (__hip_bfloat16*)d_ws;
  float* eproj = (float*)((char*)d_ws + BPACK_ELEMS * 2);
  float* hcat  = eproj;   // overlap: k_lstm writes after k_pack consumed eproj

  k_embproj<<<dim3(2 * V_), dim3(256), 0, stream>>>(emb, Wih_f, bih_f, bhh_f,
                                                    Wih_b, bih_b, bhh_b, eproj);
  k_pack<<<dim3(2 * KS_ * 64), dim3(64), 0, stream>>>(eproj, Whh_f, Whh_b, Bpack);
  k_lstm<<<dim3(NW / M_, 2), dim3(256), 0, stream>>>(char_ids, word_lens, Bpack, hcat);
  k_proj<<<dim3(NW / PM_), dim3(256), 0, stream>>>(hcat, pW, pb, out);
}

// Round 3
// 1921.406 us; speedup vs baseline: 4.0767x; 2.8920x over previous
//
#include <hip/hip_runtime.h>
#include <hip/hip_bf16.h>
#include <math.h>

// Problem constants
#define B_  64
#define W_  128
#define L_  32
#define V_  128
#define E_  128
#define H_  256
#define G4_ 1024      // 4*H
#define NW  8192      // B*W words
#define KS_ 12        // MFMA k-steps: 8 for h (K=256) + 4 for one-hot chars (V=128)
#define KPAD 408      // padded LDS row (bf16): 384 used + 24 pad (816B = 204 dw, 2-way banks)
#define M_  64        // words per block

typedef short s8v  __attribute__((ext_vector_type(8)));  // 8 bf16 (4 VGPR)
typedef float f4v  __attribute__((ext_vector_type(4)));

// ---------------------------------------------------------------------------
// K1: eproj[dir][v][g] = dot(emb[v], Wih_dir[g]) + bih[g] + bhh[g]   (fp32)
// ---------------------------------------------------------------------------
__global__ __launch_bounds__(256) void k_embproj(
    const float* __restrict__ emb,
    const float* __restrict__ Wih_f, const float* __restrict__ bih_f, const float* __restrict__ bhh_f,
    const float* __restrict__ Wih_b, const float* __restrict__ bih_b, const float* __restrict__ bhh_b,
    float* __restrict__ eproj) {
  int v   = blockIdx.x & (V_ - 1);
  int dir = blockIdx.x >> 7;
  const float* Wih = dir ? Wih_b : Wih_f;
  const float* b1  = dir ? bih_b : bih_f;
  const float* b2  = dir ? bhh_b : bhh_f;
  __shared__ float es[E_];
  if (threadIdx.x < E_) es[threadIdx.x] = emb[v * E_ + threadIdx.x];
  __syncthreads();
#pragma unroll
  for (int q = 0; q < 4; ++q) {
    int g = q * 256 + threadIdx.x;
    const float* wr = Wih + g * E_;
    float a = 0.f;
#pragma unroll 4
    for (int k = 0; k < E_; k += 4) {
      float4 w4 = *(const float4*)(wr + k);
      float4 e4 = *(const float4*)(es + k);
      a += w4.x * e4.x + w4.y * e4.y + w4.z * e4.z + w4.w * e4.w;
    }
    eproj[(dir * V_ + v) * G4_ + g] = a + b1[g] + b2[g];
  }
}

// ---------------------------------------------------------------------------
// K1b: pack B = [Whh^T ; eproj] (384 x 1024) per dir into MFMA B-fragment
// layout, bf16.  Element (ks, nt, lane, j) holds Bmat[k][n]:
//   k = ks*32 + (lane>>4)*8 + j,  n = nt*16 + (lane&15)
//   k <  256 : Whh[n][k]      (h recurrence)
//   k >= 256 : eproj[k-256][n] (one-hot char rows, biases folded in)
// ---------------------------------------------------------------------------
__global__ __launch_bounds__(64) void k_pack(
    const float* __restrict__ eproj,
    const float* __restrict__ Whh_f, const float* __restrict__ Whh_b,
    __hip_bfloat16* __restrict__ Bpack) {
  const int lane = threadIdx.x;
  const int nt   = blockIdx.x & 63;
  const int ks   = (blockIdx.x >> 6) % KS_;
  const int dir  = blockIdx.x / (64 * KS_);
  const float* Whh = dir ? Whh_b : Whh_f;
  const int n  = nt * 16 + (lane & 15);
  const int k0 = ks * 32 + (lane >> 4) * 8;
  size_t base = (((size_t)(dir * KS_ + ks) * 64 + nt) * 64 + lane) * 8;
#pragma unroll
  for (int j = 0; j < 8; ++j) {
    int k = k0 + j;
    float v = (k < H_) ? Whh[n * H_ + k]
                       : eproj[(dir * V_ + (k - H_)) * G4_ + n];
    Bpack[base + j] = __float2bfloat16(v);
  }
}

// ---------------------------------------------------------------------------
// K2: MFMA BiLSTM recurrence. Block = 64 words x 1 dir, 8 waves (512 thr).
// Wave w owns gate-columns x in {2w, 2w+1}: nt = u*16 + x  (u = gate 0..3).
// acc[u][jj][mt]: M-tile mt (words mt*16..+16), so each B fragment feeds
// 4 MFMAs.  A = [h | onehot(char)] bf16 in LDS.
// C/D layout (verified m89): word = mt*16 + (lane>>4)*4 + reg, col = lane&15.
// ---------------------------------------------------------------------------
__global__ __launch_bounds__(512, 2) void k_lstm(
    const int* __restrict__ char_ids, const int* __restrict__ word_lens,
    const __hip_bfloat16* __restrict__ Bpack, float* __restrict__ hcat) {
  const int tid  = threadIdx.x;
  const int lane = tid & 63;
  const int w    = tid >> 6;       // wave 0..7
  const int w0   = blockIdx.x * M_;
  const int dir  = blockIdx.y;     // 0 fwd, 1 bwd

  __shared__ unsigned short hL[M_][KPAD];  // 52 KB: [h 256 | onehot 128 | pad]
  __shared__ int ids_s[M_][L_];            // 8 KB
  __shared__ int len_s[M_];

  for (int i = tid; i < M_ * L_; i += 512) ((int*)ids_s)[i] = char_ids[w0 * L_ + i];
  if (tid < M_) len_s[tid] = word_lens[w0 + tid];
  for (int i = tid; i < M_ * KPAD / 2; i += 512) ((unsigned int*)hL)[i] = 0u;
  __syncthreads();

  // one-hot for t=0
  if (tid < M_) {
    int len = len_s[tid];
    int tt  = dir ? (len - 1) : 0;
    hL[tid][H_ + ids_s[tid][tt]] = 0x3F80;  // bf16 1.0
  }
  int mlen = 0;
#pragma unroll 8
  for (int m = 0; m < M_; ++m) mlen = max(mlen, len_s[m]);
  // packed lens for this lane's 16 (mt, r) words: word = mt*16 + (lane>>4)*4 + r
  unsigned lrp[4];
#pragma unroll
  for (int mt = 0; mt < 4; ++mt) {
    int bw = mt * 16 + ((lane >> 4) << 2);
    lrp[mt] = (unsigned)len_s[bw] | ((unsigned)len_s[bw + 1] << 8) |
              ((unsigned)len_s[bw + 2] << 16) | ((unsigned)len_s[bw + 3] << 24);
  }
  __syncthreads();

  const char* Bb   = (const char*)(Bpack + (size_t)dir * (KS_ * 64 * 64 * 8));
  const int   aoff = (lane >> 4) << 4;     // byte offset of this lane's 8 k-elems
  const char* ar0  = (const char*)&hL[ 0 + (lane & 15)][0];
  const char* ar1  = (const char*)&hL[16 + (lane & 15)][0];
  const char* ar2  = (const char*)&hL[32 + (lane & 15)][0];
  const char* ar3  = (const char*)&hL[48 + (lane & 15)][0];

  float c_[2][4][4];                       // [jj][mt][r]
#pragma unroll
  for (int jj = 0; jj < 2; ++jj)
#pragma unroll
    for (int mt = 0; mt < 4; ++mt)
#pragma unroll
      for (int r = 0; r < 4; ++r) c_[jj][mt][r] = 0.f;

  for (int t = 0; t < mlen; ++t) {
    f4v acc[4][2][4];                      // [gate u][jj][M-tile mt]
#pragma unroll
    for (int u = 0; u < 4; ++u)
#pragma unroll
      for (int jj = 0; jj < 2; ++jj)
#pragma unroll
        for (int mt = 0; mt < 4; ++mt) acc[u][jj][mt] = (f4v){0.f, 0.f, 0.f, 0.f};

#pragma unroll
    for (int ks = 0; ks < KS_; ++ks) {
      s8v af[4];
      af[0] = *(const s8v*)(ar0 + ks * 64 + aoff);
      af[1] = *(const s8v*)(ar1 + ks * 64 + aoff);
      af[2] = *(const s8v*)(ar2 + ks * 64 + aoff);
      af[3] = *(const s8v*)(ar3 + ks * 64 + aoff);
#pragma unroll
      for (int u = 0; u < 4; ++u) {
#pragma unroll
        for (int jj = 0; jj < 2; ++jj) {
          const int nt = u * 16 + 2 * w + jj;
          s8v bf = *(const s8v*)(Bb + (((size_t)ks * 64 + nt) * 64 + lane) * 16);
          acc[u][jj][0] = __builtin_amdgcn_mfma_f32_16x16x32_bf16(af[0], bf, acc[u][jj][0], 0, 0, 0);
          acc[u][jj][1] = __builtin_amdgcn_mfma_f32_16x16x32_bf16(af[1], bf, acc[u][jj][1], 0, 0, 0);
          acc[u][jj][2] = __builtin_amdgcn_mfma_f32_16x16x32_bf16(af[2], bf, acc[u][jj][2], 0, 0, 0);
          acc[u][jj][3] = __builtin_amdgcn_mfma_f32_16x16x32_bf16(af[3], bf, acc[u][jj][3], 0, 0, 0);
        }
      }
    }

    __syncthreads();   // all waves done reading hL for step t

    // elementwise gates + masked state update; write h_new (bf16) to LDS
#pragma unroll
    for (int jj = 0; jj < 2; ++jj) {
#pragma unroll
      for (int mt = 0; mt < 4; ++mt) {
#pragma unroll
        for (int r = 0; r < 4; ++r) {
          const int m = mt * 16 + ((lane >> 4) << 2) + r;
          const int p = (2 * w + jj) * 16 + (lane & 15);
          float gi = acc[0][jj][mt][r];
          float gf = acc[1][jj][mt][r];
          float gg = acc[2][jj][mt][r];
          float go = acc[3][jj][mt][r];
          float si = 1.f / (1.f + __expf(-gi));
          float sf = 1.f / (1.f + __expf(-gf));
          float so = 1.f / (1.f + __expf(-go));
          float tg = 2.f / (1.f + __expf(-2.f * gg)) - 1.f;
          float cn = sf * c_[jj][mt][r] + si * tg;
          float hn = so * (2.f / (1.f + __expf(-2.f * cn)) - 1.f);
          int len = (int)((lrp[mt] >> (8 * r)) & 255u);
          if (t < len) {
            c_[jj][mt][r] = cn;
            union { __hip_bfloat16 b; unsigned short u; } cv;
            cv.b = __float2bfloat16(hn);
            hL[m][p] = cv.u;
          }
        }
      }
    }
    // advance one-hot to step t+1
    if (tid < M_ && t + 1 < mlen) {
      int len  = len_s[tid];
      int told = dir ? max(len - 1 - t, 0)       : min(t, len - 1);
      int tnew = dir ? max(len - 1 - (t + 1), 0) : min(t + 1, len - 1);
      hL[tid][H_ + ids_s[tid][told]] = 0;
      hL[tid][H_ + ids_s[tid][tnew]] = 0x3F80;
    }
    __syncthreads();   // h(t+1) + one-hot(t+1) visible
  }

  // write frozen h to hcat: concat = [h_bwd | h_fwd]
  const int off = dir ? 0 : H_;
  for (int i = tid; i < M_ * H_; i += 512) {
    int q   = i >> 8;        // local word
    int pos = i & 255;
    unsigned int ui = ((unsigned int)hL[q][pos]) << 16;
    hcat[(size_t)(w0 + q) * (2 * H_) + off + pos] = __uint_as_float(ui);
  }
}

// ---------------------------------------------------------------------------
// K3: wemb = hcat @ pW^T + pb;  also writes lens_out (= W) slots.
// ---------------------------------------------------------------------------
#define PM_ 16
__global__ __launch_bounds__(256) void k_proj(
    const float* __restrict__ hcat, const float* __restrict__ pW,
    const float* __restrict__ pb, float* __restrict__ out) {
  const int tid = threadIdx.x;
  const int n0  = blockIdx.x * PM_;
  __shared__ float hs[PM_][2 * H_];   // 32 KB
  for (int i = tid; i < PM_ * 2 * H_; i += 256) ((float*)hs)[i] = hcat[n0 * 2 * H_ + i];
  __syncthreads();

  const float* pwr = pW + tid * (2 * H_);
  float acc[PM_];
#pragma unroll
  for (int m = 0; m < PM_; ++m) acc[m] = 0.f;

#pragma unroll 2
  for (int k = 0; k < 2 * H_; k += 4) {
    float4 w4 = *(const float4*)(pwr + k);
#pragma unroll
    for (int m = 0; m < PM_; ++m) {
      float4 h4 = *(const float4*)(&hs[m][k]);
      acc[m] += w4.x * h4.x + w4.y * h4.y + w4.z * h4.z + w4.w * h4.w;
    }
  }
  const float bias = pb[tid];
#pragma unroll
  for (int m = 0; m < PM_; ++m) out[(n0 + m) * H_ + tid] = acc[m] + bias;

  if (blockIdx.x == 0 && tid < B_) out[NW * H_ + tid] = (float)W_;
}

// ---------------------------------------------------------------------------
extern "C" void kernel_launch(void* const* d_in, const int* in_sizes, int n_in,
                              void* d_out, int out_size, void* d_ws, size_t ws_size,
                              hipStream_t stream) {
  const int*   char_ids  = (const int*)  d_in[0];
  const int*   word_lens = (const int*)  d_in[1];
  const float* emb       = (const float*)d_in[2];
  const float* Wih_f     = (const float*)d_in[3];
  const float* Whh_f     = (const float*)d_in[4];
  const float* bih_f     = (const float*)d_in[5];
  const float* bhh_f     = (const float*)d_in[6];
  const float* Wih_b     = (const float*)d_in[7];
  const float* Whh_b     = (const float*)d_in[8];
  const float* bih_b     = (const float*)d_in[9];
  const float* bhh_b     = (const float*)d_in[10];
  const float* pW        = (const float*)d_in[11];
  const float* pb        = (const float*)d_in[12];
  float* out = (float*)d_out;

  // ws: [Bpack 1.5MB][eproj 1MB / hcat 16MB union]  (eproj dead after k_pack)
  const size_t BPACK_ELEMS = (size_t)2 * KS_ * 64 * 64 * 8;
  __hip_bfloat16* Bpack = (__hip_bfloat16*)d_ws;
  float* eproj = (float*)((char*)d_ws + BPACK_ELEMS * 2);
  float* hcat  = eproj;   // overlap: k_lstm writes after k_pack consumed eproj

  k_embproj<<<dim3(2 * V_), dim3(256), 0, stream>>>(emb, Wih_f, bih_f, bhh_f,
                                                    Wih_b, bih_b, bhh_b, eproj);
  k_pack<<<dim3(2 * KS_ * 64), dim3(64), 0, stream>>>(eproj, Whh_f, Whh_b, Bpack);
  k_lstm<<<dim3(NW / M_, 2), dim3(512), 0, stream>>>(char_ids, word_lens, Bpack, hcat);
  k_proj<<<dim3(NW / PM_), dim3(256), 0, stream>>>(hcat, pW, pb, out);
}